// Round 1
// baseline (662.800 us; speedup 1.0000x reference)
//
#include <hip/hip_runtime.h>
#include <stdint.h>

typedef short bf16x8 __attribute__((ext_vector_type(8)));
typedef float f32x4 __attribute__((ext_vector_type(4)));

// RNE float -> bf16 (raw bits in short)
__device__ __forceinline__ short f2bf(float f) {
  unsigned int u = __float_as_uint(f);
  u = (u + 0x7FFFu + ((u >> 16) & 1u)) >> 16;
  return (short)u;
}

// ---------------------------------------------------------------------------
// Prep kernels
// ---------------------------------------------------------------------------

// fp32 -> bf16 elementwise, 4 elems/thread
__global__ void cvt_x_kernel(const float* __restrict__ in, short* __restrict__ out) {
  int i = blockIdx.x * 256 + threadIdx.x;
  float4 v = ((const float4*)in)[i];
  short4 o;
  o.x = f2bf(v.x); o.y = f2bf(v.y); o.z = f2bf(v.z); o.w = f2bf(v.w);
  ((short4*)out)[i] = o;
}

// out[c][r] = bf16(in[r][c]);  R,C multiples of 32
__global__ void transpose_f2b_kernel(const float* __restrict__ in, short* __restrict__ out,
                                     int R, int C) {
  __shared__ float tile[32][33];
  int tx = threadIdx.x & 31, ty = threadIdx.x >> 5;
  int c0 = blockIdx.x * 32, r0 = blockIdx.y * 32;
#pragma unroll
  for (int j = 0; j < 4; j++)
    tile[ty + j * 8][tx] = in[(size_t)(r0 + ty + j * 8) * C + c0 + tx];
  __syncthreads();
#pragma unroll
  for (int j = 0; j < 4; j++)
    out[(size_t)(c0 + ty + j * 8) * R + r0 + tx] = f2bf(tile[tx][ty + j * 8]);
}

// vT[bh][d][l] = qkv[b*2048+l][2048 + h*64 + d]   (bf16 -> bf16 transpose)
__global__ void transpose_v_kernel(const short* __restrict__ qkv, short* __restrict__ vT) {
  __shared__ short tile[32][33];
  int tx = threadIdx.x & 31, ty = threadIdx.x >> 5;
  int l0 = blockIdx.x * 32, d0 = blockIdx.y * 32;
  int bh = blockIdx.z, b = bh >> 4, h = bh & 15;
#pragma unroll
  for (int j = 0; j < 4; j++)
    tile[ty + j * 8][tx] =
        qkv[(size_t)(b * 2048 + l0 + ty + j * 8) * 3072 + 2048 + h * 64 + d0 + tx];
  __syncthreads();
#pragma unroll
  for (int j = 0; j < 4; j++)
    vT[((size_t)bh * 64 + d0 + ty + j * 8) * 2048 + l0 + tx] = tile[tx][ty + j * 8];
}

// T5 relative-position bias table: btab[h][dist] , dist = q - k in [0,2047]
__global__ void bias_kernel(const float* __restrict__ rel_emb, float* __restrict__ btab) {
  int i = blockIdx.x * 256 + threadIdx.x;  // 16*2048
  int h = i >> 11, n = i & 2047;
  int bucket;
  if (n < 16) {
    bucket = n;
  } else {
    // 16 + trunc( log(n/16)/log(8) * 16 ), clamped to 31
    float t = logf((float)n * 0.0625f) * (16.0f / 2.0794415416798357f);
    bucket = 16 + (int)t;
    if (bucket > 31) bucket = 31;
  }
  btab[i] = rel_emb[bucket * 16 + h];
}

// ---------------------------------------------------------------------------
// bf16 GEMM:  C[M][N] = A[M][K] * Bt[N][K]^T   (both bf16, fp32 accumulate)
// 128x128 tile, BK=64, 4 waves (2x2 of 64x64), 16x16x32 MFMA.
// EPI: 0 = bf16 store, 1 = relu->bf16, 2 = fp32 store, 3 = fp32 (+add1+add2)
// ---------------------------------------------------------------------------
template <int EPI>
__global__ __launch_bounds__(256, 2)
void gemm_bt_kernel(const short* __restrict__ A, const short* __restrict__ Bt,
                    int N, int K,
                    float* __restrict__ Cf, short* __restrict__ Cb,
                    const float* __restrict__ add1, const float* __restrict__ add2) {
  // padded rows (72 shorts = 144B, 16B-aligned, conflict-free b128 frag reads)
  __shared__ short lA[128 * 72];
  __shared__ short lB[128 * 72];
  const int t = threadIdx.x;
  const int w = t >> 6, lane = t & 63;
  const int q4 = lane >> 4, l15 = lane & 15;
  const int mBase = blockIdx.y * 128, nBase = blockIdx.x * 128;
  const int wm = (w >> 1) * 64, wn = (w & 1) * 64;
  const int sr = t >> 1;          // staging row 0..127
  const int sg = (t & 1) * 32;    // staging element offset 0 / 32

  const f32x4 fzero = {0.f, 0.f, 0.f, 0.f};
  f32x4 acc[4][4];
#pragma unroll
  for (int i = 0; i < 4; i++)
#pragma unroll
    for (int j = 0; j < 4; j++) acc[i][j] = fzero;

  const short* Ap = A + (size_t)(mBase + sr) * K + sg;
  const short* Bp = Bt + (size_t)(nBase + sr) * K + sg;

  for (int k0 = 0; k0 < K; k0 += 64) {
    int4 ra0 = *(const int4*)(Ap + k0);
    int4 ra1 = *(const int4*)(Ap + k0 + 8);
    int4 ra2 = *(const int4*)(Ap + k0 + 16);
    int4 ra3 = *(const int4*)(Ap + k0 + 24);
    int4 rb0 = *(const int4*)(Bp + k0);
    int4 rb1 = *(const int4*)(Bp + k0 + 8);
    int4 rb2 = *(const int4*)(Bp + k0 + 16);
    int4 rb3 = *(const int4*)(Bp + k0 + 24);
    __syncthreads();  // previous iteration's frag reads done
    *(int4*)&lA[sr * 72 + sg]      = ra0;
    *(int4*)&lA[sr * 72 + sg + 8]  = ra1;
    *(int4*)&lA[sr * 72 + sg + 16] = ra2;
    *(int4*)&lA[sr * 72 + sg + 24] = ra3;
    *(int4*)&lB[sr * 72 + sg]      = rb0;
    *(int4*)&lB[sr * 72 + sg + 8]  = rb1;
    *(int4*)&lB[sr * 72 + sg + 16] = rb2;
    *(int4*)&lB[sr * 72 + sg + 24] = rb3;
    __syncthreads();
#pragma unroll
    for (int ks = 0; ks < 2; ks++) {
      bf16x8 af[4], bfr[4];
#pragma unroll
      for (int mi = 0; mi < 4; mi++)
        af[mi] = *(const bf16x8*)&lA[(wm + mi * 16 + l15) * 72 + ks * 32 + q4 * 8];
#pragma unroll
      for (int ni = 0; ni < 4; ni++)
        bfr[ni] = *(const bf16x8*)&lB[(wn + ni * 16 + l15) * 72 + ks * 32 + q4 * 8];
#pragma unroll
      for (int mi = 0; mi < 4; mi++)
#pragma unroll
        for (int ni = 0; ni < 4; ni++)
          acc[mi][ni] =
              __builtin_amdgcn_mfma_f32_16x16x32_bf16(af[mi], bfr[ni], acc[mi][ni], 0, 0, 0);
    }
  }

  // C/D layout: col = lane&15, row = (lane>>4)*4 + reg
#pragma unroll
  for (int mi = 0; mi < 4; mi++)
#pragma unroll
    for (int ni = 0; ni < 4; ni++) {
#pragma unroll
      for (int r = 0; r < 4; r++) {
        size_t idx = (size_t)(mBase + wm + mi * 16 + q4 * 4 + r) * N +
                     (nBase + wn + ni * 16 + l15);
        float v = acc[mi][ni][r];
        if constexpr (EPI == 0) Cb[idx] = f2bf(v);
        else if constexpr (EPI == 1) Cb[idx] = f2bf(v > 0.f ? v : 0.f);
        else if constexpr (EPI == 2) Cf[idx] = v;
        else Cf[idx] = v + add1[idx] + add2[idx];
      }
    }
}

// ---------------------------------------------------------------------------
// Flash attention, causal + T5 relpos bias.
// Grid: (L/64, B*H). Block: 256 (4 waves); wave w owns q rows w*16..w*16+15.
// qkv: [8192][3072] bf16 (q|k|v).  vT: [64 bh][64 d][2048 l] bf16.
// ctx out: [8192][1024] bf16 (l, h*64+d).
// ---------------------------------------------------------------------------
__global__ __launch_bounds__(256, 2)
void attn_kernel(const short* __restrict__ qkv, const short* __restrict__ vT,
                 const float* __restrict__ bias_tab, short* __restrict__ ctx) {
  __shared__ short lK[64 * 72];      // [kpos][d]
  __shared__ short lV[64 * 72];      // [d][kpos]  (V^T tile)
  __shared__ short lP[4][16 * 72];   // per-wave P round-trip

  const int t = threadIdx.x, w = t >> 6, lane = t & 63;
  const int q4 = lane >> 4, l15 = lane & 15;
  const int qt = blockIdx.x;     // 0..31
  const int bh = blockIdx.y;     // 0..63
  const int b = bh >> 4, h = bh & 15;
  const int q0 = qt * 64;
  const f32x4 fzero = {0.f, 0.f, 0.f, 0.f};

  // Q A-fragments (A[m=lane&15][k=quad*8+j]), rows q0 + w*16 + l15
  const size_t qrow = (size_t)(b * 2048 + q0 + w * 16 + l15) * 3072 + h * 64;
  bf16x8 aq0 = *(const bf16x8*)(qkv + qrow + q4 * 8);
  bf16x8 aq1 = *(const bf16x8*)(qkv + qrow + 32 + q4 * 8);

  f32x4 vacc[4];
#pragma unroll
  for (int db = 0; db < 4; db++) vacc[db] = fzero;
  float m_old[4], l_sum[4];
#pragma unroll
  for (int r = 0; r < 4; r++) { m_old[r] = -3.0e38f; l_sum[r] = 0.f; }

  const float* btab = bias_tab + h * 2048;
  const int srow = t >> 2;            // staging row 0..63
  const int sge = (t & 3) * 8;        // staging element 0/8/16/24 (+32 pair)
  const int qrow0 = q0 + w * 16 + q4 * 4;  // + r gives absolute q row
  const float L2E = 1.44269504088896f;

  for (int kt = 0; kt <= qt; kt++) {
    const short* kp =
        qkv + (size_t)(b * 2048 + kt * 64 + srow) * 3072 + 1024 + h * 64 + sge;
    int4 rk0 = *(const int4*)kp;
    int4 rk1 = *(const int4*)(kp + 32);
    const short* vp = vT + ((size_t)bh * 64 + srow) * 2048 + kt * 64 + sge;
    int4 rv0 = *(const int4*)vp;
    int4 rv1 = *(const int4*)(vp + 32);
    __syncthreads();
    *(int4*)&lK[srow * 72 + sge]      = rk0;
    *(int4*)&lK[srow * 72 + sge + 32] = rk1;
    *(int4*)&lV[srow * 72 + sge]      = rv0;
    *(int4*)&lV[srow * 72 + sge + 32] = rv1;
    __syncthreads();

    // S = Q K^T   (C layout: col=l15 -> kpos, row=q4*4+r -> q)
    float s[4][4];
#pragma unroll
    for (int nb = 0; nb < 4; nb++) {
      bf16x8 bk0 = *(const bf16x8*)&lK[(nb * 16 + l15) * 72 + q4 * 8];
      bf16x8 bk1 = *(const bf16x8*)&lK[(nb * 16 + l15) * 72 + 32 + q4 * 8];
      f32x4 f = fzero;
      f = __builtin_amdgcn_mfma_f32_16x16x32_bf16(aq0, bk0, f, 0, 0, 0);
      f = __builtin_amdgcn_mfma_f32_16x16x32_bf16(aq1, bk1, f, 0, 0, 0);
#pragma unroll
      for (int r = 0; r < 4; r++) s[nb][r] = f[r];
    }

    // scale + bias + causal mask
#pragma unroll
    for (int nb = 0; nb < 4; nb++) {
      const int kcol = kt * 64 + nb * 16 + l15;
#pragma unroll
      for (int r = 0; r < 4; r++) {
        int dist = (qrow0 + r) - kcol;
        float bv = btab[dist < 0 ? 0 : dist];
        float sv = s[nb][r] * 0.125f + bv;
        s[nb][r] = (dist < 0) ? -3.0e38f : sv;
      }
    }

    // online softmax
    float mnew[4], alpha[4];
#pragma unroll
    for (int r = 0; r < 4; r++) {
      float mx = fmaxf(fmaxf(s[0][r], s[1][r]), fmaxf(s[2][r], s[3][r]));
      mx = fmaxf(mx, __shfl_xor(mx, 1));
      mx = fmaxf(mx, __shfl_xor(mx, 2));
      mx = fmaxf(mx, __shfl_xor(mx, 4));
      mx = fmaxf(mx, __shfl_xor(mx, 8));
      mnew[r] = fmaxf(m_old[r], mx);
      alpha[r] = __builtin_amdgcn_exp2f((m_old[r] - mnew[r]) * L2E);
      m_old[r] = mnew[r];
    }
#pragma unroll
    for (int nb = 0; nb < 4; nb++)
#pragma unroll
      for (int r = 0; r < 4; r++)
        s[nb][r] = __builtin_amdgcn_exp2f((s[nb][r] - mnew[r]) * L2E);
#pragma unroll
    for (int r = 0; r < 4; r++) {
      float ps = s[0][r] + s[1][r] + s[2][r] + s[3][r];
      ps += __shfl_xor(ps, 1);
      ps += __shfl_xor(ps, 2);
      ps += __shfl_xor(ps, 4);
      ps += __shfl_xor(ps, 8);
      l_sum[r] = l_sum[r] * alpha[r] + ps;
    }
#pragma unroll
    for (int db = 0; db < 4; db++)
#pragma unroll
      for (int r = 0; r < 4; r++) vacc[db][r] *= alpha[r];

    // P: C-layout -> LDS -> A-layout (per-wave buffer, no barrier needed)
    short* lPw = lP[w];
#pragma unroll
    for (int nb = 0; nb < 4; nb++)
#pragma unroll
      for (int r = 0; r < 4; r++)
        lPw[(q4 * 4 + r) * 72 + nb * 16 + l15] = f2bf(s[nb][r]);

    bf16x8 ap0 = *(const bf16x8*)&lPw[l15 * 72 + q4 * 8];
    bf16x8 ap1 = *(const bf16x8*)&lPw[l15 * 72 + 32 + q4 * 8];
#pragma unroll
    for (int db = 0; db < 4; db++) {
      bf16x8 bv0 = *(const bf16x8*)&lV[(db * 16 + l15) * 72 + q4 * 8];
      bf16x8 bv1 = *(const bf16x8*)&lV[(db * 16 + l15) * 72 + 32 + q4 * 8];
      vacc[db] = __builtin_amdgcn_mfma_f32_16x16x32_bf16(ap0, bv0, vacc[db], 0, 0, 0);
      vacc[db] = __builtin_amdgcn_mfma_f32_16x16x32_bf16(ap1, bv1, vacc[db], 0, 0, 0);
    }
  }

  // epilogue: ctx = vacc / l_sum  (l_sum >= 1 always on the causal diagonal)
  float inv[4];
#pragma unroll
  for (int r = 0; r < 4; r++) inv[r] = 1.0f / l_sum[r];
#pragma unroll
  for (int db = 0; db < 4; db++)
#pragma unroll
    for (int r = 0; r < 4; r++) {
      size_t idx = (size_t)(b * 2048 + q0 + w * 16 + q4 * 4 + r) * 1024 +
                   h * 64 + db * 16 + l15;
      ctx[idx] = f2bf(vacc[db][r] * inv[r]);
    }
}

// ---------------------------------------------------------------------------
// Launch
// ---------------------------------------------------------------------------
extern "C" void kernel_launch(void* const* d_in, const int* in_sizes, int n_in,
                              void* d_out, int out_size, void* d_ws, size_t ws_size,
                              hipStream_t stream) {
  (void)in_sizes; (void)n_in; (void)out_size; (void)ws_size;
  const float* inputs  = (const float*)d_in[0];  // [4,2048,1024]
  const float* wq      = (const float*)d_in[1];  // [1024,16,64]
  const float* wk      = (const float*)d_in[2];
  const float* wv      = (const float*)d_in[3];
  const float* wo      = (const float*)d_in[4];  // [16,64,1024]
  const float* wi      = (const float*)d_in[5];  // [1024,4096]
  const float* wmo     = (const float*)d_in[6];  // [4096,1024]
  const float* rel_emb = (const float*)d_in[7];  // [32,16]
  float* out = (float*)d_out;                    // [4,2048,1024] fp32
  char* ws = (char*)d_ws;

  const size_t MB = 1ull << 20;
  short* x16    = (short*)(ws + 0);        // 16 MB  [8192][1024] bf16
  short* qkv    = (short*)(ws + 16 * MB);  // 48 MB  [8192][3072] bf16
  short* hidden = (short*)(ws + 16 * MB);  // 64 MB  overlay (qkv+vT dead by then)
  short* vT     = (short*)(ws + 64 * MB);  // 16 MB  [64][64][2048] bf16
  short* wqkvt  = (short*)(ws + 80 * MB);  // 6 MB   [3072][1024] bf16
  short* wot    = (short*)(ws + 86 * MB);  // 2 MB   [1024][1024] bf16
  short* wit    = (short*)(ws + 88 * MB);  // 8 MB   [4096][1024] bf16
  short* wmot   = (short*)(ws + 96 * MB);  // 8 MB   [1024][4096] bf16
  float* btab   = (float*)(ws + 104 * MB); // 128 KB [16][2048] fp32
  short* ctx    = (short*)(ws + 105 * MB); // 16 MB  [8192][1024] bf16
  // peak ws use: 121 MB. hidden overlays [16MB,83MB): clobbers 3MB of wqkvt,
  // which is re-written at the top of every call before GEMM1 uses it -> safe.

  // prep
  cvt_x_kernel<<<8192, 256, 0, stream>>>(inputs, x16);
  transpose_f2b_kernel<<<dim3(32, 32), 256, 0, stream>>>(wq, wqkvt, 1024, 1024);
  transpose_f2b_kernel<<<dim3(32, 32), 256, 0, stream>>>(wk, wqkvt + 1024 * 1024, 1024, 1024);
  transpose_f2b_kernel<<<dim3(32, 32), 256, 0, stream>>>(wv, wqkvt + 2 * 1024 * 1024, 1024, 1024);
  transpose_f2b_kernel<<<dim3(32, 32), 256, 0, stream>>>(wo, wot, 1024, 1024);
  transpose_f2b_kernel<<<dim3(128, 32), 256, 0, stream>>>(wi, wit, 1024, 4096);
  transpose_f2b_kernel<<<dim3(32, 128), 256, 0, stream>>>(wmo, wmot, 4096, 1024);
  bias_kernel<<<128, 256, 0, stream>>>(rel_emb, btab);

  // qkv = x @ [wq|wk|wv]   (M=8192, N=3072, K=1024), bf16 out
  gemm_bt_kernel<0><<<dim3(24, 64), 256, 0, stream>>>(x16, wqkvt, 3072, 1024,
                                                      nullptr, qkv, nullptr, nullptr);
  // V^T for PV operand
  transpose_v_kernel<<<dim3(64, 2, 64), 256, 0, stream>>>(qkv, vT);
  // attention -> ctx (bf16)
  attn_kernel<<<dim3(32, 64), 256, 0, stream>>>(qkv, vT, btab, ctx);
  // attn_out = ctx @ wo -> d_out (fp32, reused as scratch)
  gemm_bt_kernel<2><<<dim3(8, 64), 256, 0, stream>>>(ctx, wot, 1024, 1024,
                                                     out, nullptr, nullptr, nullptr);
  // hidden = relu(x @ wi)  (N=4096, K=1024), bf16 out
  gemm_bt_kernel<1><<<dim3(32, 64), 256, 0, stream>>>(x16, wit, 4096, 1024,
                                                      nullptr, hidden, nullptr, nullptr);
  // out = hidden @ wmo + inputs + attn_out  (N=1024, K=4096)
  gemm_bt_kernel<3><<<dim3(8, 64), 256, 0, stream>>>(hidden, wmot, 1024, 4096,
                                                     out, nullptr, inputs, out);
}

// Round 2
// 554.348 us; speedup vs baseline: 1.1956x; 1.1956x over previous
//
#include <hip/hip_runtime.h>
#include <stdint.h>

typedef short bf16x8 __attribute__((ext_vector_type(8)));
typedef float f32x4 __attribute__((ext_vector_type(4)));

// RNE float -> bf16 (raw bits in short)
__device__ __forceinline__ short f2bf(float f) {
  unsigned int u = __float_as_uint(f);
  u = (u + 0x7FFFu + ((u >> 16) & 1u)) >> 16;
  return (short)u;
}

// async global->LDS, 16B per lane. LDS dest = wave-uniform base + lane*16.
__device__ __forceinline__ void gload_lds16(const void* g, void* l) {
  __builtin_amdgcn_global_load_lds((const __attribute__((address_space(1))) void*)g,
                                   (__attribute__((address_space(3))) void*)l, 16, 0, 0);
}

// ---------------------------------------------------------------------------
// Prep kernels
// ---------------------------------------------------------------------------

__global__ void cvt_x_kernel(const float* __restrict__ in, short* __restrict__ out) {
  int i = blockIdx.x * 256 + threadIdx.x;
  float4 v = ((const float4*)in)[i];
  short4 o;
  o.x = f2bf(v.x); o.y = f2bf(v.y); o.z = f2bf(v.z); o.w = f2bf(v.w);
  ((short4*)out)[i] = o;
}

// out[c][r] = bf16(in[r][c]);  R,C multiples of 32
__global__ void transpose_f2b_kernel(const float* __restrict__ in, short* __restrict__ out,
                                     int R, int C) {
  __shared__ float tile[32][33];
  int tx = threadIdx.x & 31, ty = threadIdx.x >> 5;
  int c0 = blockIdx.x * 32, r0 = blockIdx.y * 32;
#pragma unroll
  for (int j = 0; j < 4; j++)
    tile[ty + j * 8][tx] = in[(size_t)(r0 + ty + j * 8) * C + c0 + tx];
  __syncthreads();
#pragma unroll
  for (int j = 0; j < 4; j++)
    out[(size_t)(c0 + ty + j * 8) * R + r0 + tx] = f2bf(tile[tx][ty + j * 8]);
}

// vT[bh][d][l] = qkv[b*2048+l][2048 + h*64 + d]
__global__ void transpose_v_kernel(const short* __restrict__ qkv, short* __restrict__ vT) {
  __shared__ short tile[32][33];
  int tx = threadIdx.x & 31, ty = threadIdx.x >> 5;
  int l0 = blockIdx.x * 32, d0 = blockIdx.y * 32;
  int bh = blockIdx.z, b = bh >> 4, h = bh & 15;
#pragma unroll
  for (int j = 0; j < 4; j++)
    tile[ty + j * 8][tx] =
        qkv[(size_t)(b * 2048 + l0 + ty + j * 8) * 3072 + 2048 + h * 64 + d0 + tx];
  __syncthreads();
#pragma unroll
  for (int j = 0; j < 4; j++)
    vT[((size_t)bh * 64 + d0 + ty + j * 8) * 2048 + l0 + tx] = tile[tx][ty + j * 8];
}

// T5 relative-position bias table: btab[h][dist], dist = q - k in [0,2047]
__global__ void bias_kernel(const float* __restrict__ rel_emb, float* __restrict__ btab) {
  int i = blockIdx.x * 256 + threadIdx.x;  // 16*2048
  int h = i >> 11, n = i & 2047;
  int bucket;
  if (n < 16) {
    bucket = n;
  } else {
    float t = logf((float)n * 0.0625f) * (16.0f / 2.0794415416798357f);
    bucket = 16 + (int)t;
    if (bucket > 31) bucket = 31;
  }
  btab[i] = rel_emb[bucket * 16 + h];
}

// ---------------------------------------------------------------------------
// bf16 GEMM: C[M][N] = A[M][K] * Bt[N][K]^T.  128x128 tile, BK=64, 4 waves.
// m97 structure: global_load_lds(16B) staging into unpadded [128][64] tiles
// with XOR-rotate chunk swizzle (chunk kc of row r stored at slot (kc+r)&7)
// -> conflict-free b128 frag reads, unchanged global coalescing.
// EPI: 0 = bf16, 1 = relu->bf16, 2 = fp32, 3 = fp32 + add1 + add2
// ---------------------------------------------------------------------------
template <int EPI>
__global__ __launch_bounds__(256, 2)
void gemm_bt_kernel(const short* __restrict__ A, const short* __restrict__ Bt,
                    int N, int K,
                    float* __restrict__ Cf, short* __restrict__ Cb,
                    const float* __restrict__ add1, const float* __restrict__ add2) {
  __shared__ short lA[128 * 64];
  __shared__ short lB[128 * 64];
  const int t = threadIdx.x;
  const int w = t >> 6, lane = t & 63;
  const int q4 = lane >> 4, l15 = lane & 15;
  const int mBase = blockIdx.y * 128, nBase = blockIdx.x * 128;
  const int wm = (w >> 1) * 64, wn = (w & 1) * 64;

  const f32x4 fzero = {0.f, 0.f, 0.f, 0.f};
  f32x4 acc[4][4];
#pragma unroll
  for (int i = 0; i < 4; i++)
#pragma unroll
    for (int j = 0; j < 4; j++) acc[i][j] = fzero;

  for (int k0 = 0; k0 < K; k0 += 64) {
    __syncthreads();  // prior iteration's frag reads done
#pragma unroll
    for (int p = 0; p < 4; p++) {
      int c = p * 256 + t;
      int row = c >> 3;
      int kc = ((c & 7) - row) & 7;  // logical k-chunk stored at slot c&7
      gload_lds16(A + (size_t)(mBase + row) * K + k0 + kc * 8, lA + (size_t)(c - lane) * 8);
      gload_lds16(Bt + (size_t)(nBase + row) * K + k0 + kc * 8, lB + (size_t)(c - lane) * 8);
    }
    __syncthreads();  // staging visible (vmcnt drained by barrier)
#pragma unroll
    for (int ks = 0; ks < 2; ks++) {
      bf16x8 af[4], bfr[4];
#pragma unroll
      for (int mi = 0; mi < 4; mi++) {
        int row = wm + mi * 16 + l15;
        af[mi] = *(const bf16x8*)&lA[row * 64 + ((ks * 4 + q4 + row) & 7) * 8];
      }
#pragma unroll
      for (int ni = 0; ni < 4; ni++) {
        int row = wn + ni * 16 + l15;
        bfr[ni] = *(const bf16x8*)&lB[row * 64 + ((ks * 4 + q4 + row) & 7) * 8];
      }
#pragma unroll
      for (int mi = 0; mi < 4; mi++)
#pragma unroll
        for (int ni = 0; ni < 4; ni++)
          acc[mi][ni] =
              __builtin_amdgcn_mfma_f32_16x16x32_bf16(af[mi], bfr[ni], acc[mi][ni], 0, 0, 0);
    }
  }

  // C/D layout: col = lane&15, row = (lane>>4)*4 + reg
#pragma unroll
  for (int mi = 0; mi < 4; mi++)
#pragma unroll
    for (int ni = 0; ni < 4; ni++) {
#pragma unroll
      for (int r = 0; r < 4; r++) {
        size_t idx = (size_t)(mBase + wm + mi * 16 + q4 * 4 + r) * N +
                     (nBase + wn + ni * 16 + l15);
        float v = acc[mi][ni][r];
        if constexpr (EPI == 0) Cb[idx] = f2bf(v);
        else if constexpr (EPI == 1) Cb[idx] = f2bf(v > 0.f ? v : 0.f);
        else if constexpr (EPI == 2) Cf[idx] = v;
        else Cf[idx] = v + add1[idx] + add2[idx];
      }
    }
}

// ---------------------------------------------------------------------------
// Flash attention, causal + T5 relpos bias.  K-tile 128, Q-tile 64, 4 waves.
// Grid (64 bh, 32 yy), qt = 31-yy (heavy blocks first).  Register prefetch of
// next K/V tile + bias row issued after the consume barrier (overlaps compute).
// ---------------------------------------------------------------------------
__global__ __launch_bounds__(256, 2)
void attn_kernel(const short* __restrict__ qkv, const short* __restrict__ vT,
                 const float* __restrict__ bias_tab, short* __restrict__ ctx) {
  __shared__ short lK[128 * 72];     // [kpos][d]
  __shared__ short lV[64 * 136];     // [d][kpos]  (V^T tile)
  __shared__ short lP[4][16 * 136];  // per-wave P round-trip
  __shared__ float lBias[192];

  const int t = threadIdx.x, w = t >> 6, lane = t & 63;
  const int q4 = lane >> 4, l15 = lane & 15;
  const int bh = blockIdx.x;            // 0..63
  const int qt = 31 - blockIdx.y;       // heavy first
  const int b = bh >> 4, h = bh & 15;
  const int q0 = qt * 64;
  const int ntiles = (qt + 2) >> 1;     // 128-wide K tiles covering [0, q0+64)
  const f32x4 fzero = {0.f, 0.f, 0.f, 0.f};

  // Q A-fragments, rows q0 + w*16 + l15
  const size_t qrow = (size_t)(b * 2048 + q0 + w * 16 + l15) * 3072 + h * 64;
  bf16x8 aq0 = *(const bf16x8*)(qkv + qrow + q4 * 8);
  bf16x8 aq1 = *(const bf16x8*)(qkv + qrow + 32 + q4 * 8);

  f32x4 vacc[4];
#pragma unroll
  for (int db = 0; db < 4; db++) vacc[db] = fzero;
  float m_old[4], l_sum[4];
#pragma unroll
  for (int r = 0; r < 4; r++) { m_old[r] = -3.0e38f; l_sum[r] = 0.f; }

  const float* btab = bias_tab + h * 2048;
  const int ksr = t >> 1, ksg = (t & 1) * 32;  // K staging: 128 rows x 64
  const int vsr = t >> 2, vsg = (t & 3) * 32;  // V staging: 64 rows x 128
  const int qrow0 = q0 + w * 16 + q4 * 4;
  const int bofs = w * 16 + q4 * 4 + 127 - l15;  // bias LDS base index
  const float L2E = 1.44269504088896f;

  int4 rk0, rk1, rk2, rk3, rv0, rv1, rv2, rv3;
  float biasreg;
  {
    const short* kp = qkv + (size_t)(b * 2048 + ksr) * 3072 + 1024 + h * 64 + ksg;
    rk0 = *(const int4*)kp; rk1 = *(const int4*)(kp + 8);
    rk2 = *(const int4*)(kp + 16); rk3 = *(const int4*)(kp + 24);
    const short* vp = vT + ((size_t)bh * 64 + vsr) * 2048 + vsg;
    rv0 = *(const int4*)vp; rv1 = *(const int4*)(vp + 8);
    rv2 = *(const int4*)(vp + 16); rv3 = *(const int4*)(vp + 24);
    int d = q0 - 127 + t;
    d = d < 0 ? 0 : (d > 2047 ? 2047 : d);
    biasreg = btab[d];
  }

  for (int kt = 0; kt < ntiles; kt++) {
    __syncthreads();  // prior tile's LDS reads done; prefetched regs arrived
    *(int4*)&lK[ksr * 72 + ksg]      = rk0;
    *(int4*)&lK[ksr * 72 + ksg + 8]  = rk1;
    *(int4*)&lK[ksr * 72 + ksg + 16] = rk2;
    *(int4*)&lK[ksr * 72 + ksg + 24] = rk3;
    *(int4*)&lV[vsr * 136 + vsg]      = rv0;
    *(int4*)&lV[vsr * 136 + vsg + 8]  = rv1;
    *(int4*)&lV[vsr * 136 + vsg + 16] = rv2;
    *(int4*)&lV[vsr * 136 + vsg + 24] = rv3;
    if (t < 192) lBias[t] = biasreg;
    __syncthreads();  // staging visible

    if (kt + 1 < ntiles) {  // prefetch next tile — latency hides behind compute
      const short* kp =
          qkv + (size_t)(b * 2048 + (kt + 1) * 128 + ksr) * 3072 + 1024 + h * 64 + ksg;
      rk0 = *(const int4*)kp; rk1 = *(const int4*)(kp + 8);
      rk2 = *(const int4*)(kp + 16); rk3 = *(const int4*)(kp + 24);
      const short* vp = vT + ((size_t)bh * 64 + vsr) * 2048 + (kt + 1) * 128 + vsg;
      rv0 = *(const int4*)vp; rv1 = *(const int4*)(vp + 8);
      rv2 = *(const int4*)(vp + 16); rv3 = *(const int4*)(vp + 24);
      int d = q0 - (kt + 1) * 128 - 127 + t;
      d = d < 0 ? 0 : (d > 2047 ? 2047 : d);
      biasreg = btab[d];
    }

    // S = Q K^T  (8 col-blocks of 16)
    float s[8][4];
#pragma unroll
    for (int nb = 0; nb < 8; nb++) {
      bf16x8 bk0 = *(const bf16x8*)&lK[(nb * 16 + l15) * 72 + q4 * 8];
      bf16x8 bk1 = *(const bf16x8*)&lK[(nb * 16 + l15) * 72 + 32 + q4 * 8];
      f32x4 f = fzero;
      f = __builtin_amdgcn_mfma_f32_16x16x32_bf16(aq0, bk0, f, 0, 0, 0);
      f = __builtin_amdgcn_mfma_f32_16x16x32_bf16(aq1, bk1, f, 0, 0, 0);
#pragma unroll
      for (int r = 0; r < 4; r++) s[nb][r] = f[r];
    }

    // scale + bias (from LDS) + causal mask
#pragma unroll
    for (int nb = 0; nb < 8; nb++) {
      const int kcol = kt * 128 + nb * 16 + l15;
#pragma unroll
      for (int r = 0; r < 4; r++) {
        int dist = (qrow0 + r) - kcol;
        float bv = lBias[bofs + r - nb * 16];
        float sv = s[nb][r] * 0.125f + bv;
        s[nb][r] = (dist < 0) ? -3.0e38f : sv;
      }
    }

    // online softmax
    float mnew[4], alpha[4];
#pragma unroll
    for (int r = 0; r < 4; r++) {
      float mx = s[0][r];
#pragma unroll
      for (int nb = 1; nb < 8; nb++) mx = fmaxf(mx, s[nb][r]);
      mx = fmaxf(mx, __shfl_xor(mx, 1));
      mx = fmaxf(mx, __shfl_xor(mx, 2));
      mx = fmaxf(mx, __shfl_xor(mx, 4));
      mx = fmaxf(mx, __shfl_xor(mx, 8));
      mnew[r] = fmaxf(m_old[r], mx);
      alpha[r] = __builtin_amdgcn_exp2f((m_old[r] - mnew[r]) * L2E);
      m_old[r] = mnew[r];
    }
#pragma unroll
    for (int nb = 0; nb < 8; nb++)
#pragma unroll
      for (int r = 0; r < 4; r++)
        s[nb][r] = __builtin_amdgcn_exp2f((s[nb][r] - mnew[r]) * L2E);
#pragma unroll
    for (int r = 0; r < 4; r++) {
      float ps = s[0][r];
#pragma unroll
      for (int nb = 1; nb < 8; nb++) ps += s[nb][r];
      ps += __shfl_xor(ps, 1);
      ps += __shfl_xor(ps, 2);
      ps += __shfl_xor(ps, 4);
      ps += __shfl_xor(ps, 8);
      l_sum[r] = l_sum[r] * alpha[r] + ps;
    }
#pragma unroll
    for (int db = 0; db < 4; db++)
#pragma unroll
      for (int r = 0; r < 4; r++) vacc[db][r] *= alpha[r];

    // P: C-layout -> LDS -> A-layout (per-wave buffer)
    short* lPw = lP[w];
#pragma unroll
    for (int nb = 0; nb < 8; nb++)
#pragma unroll
      for (int r = 0; r < 4; r++)
        lPw[(q4 * 4 + r) * 136 + nb * 16 + l15] = f2bf(s[nb][r]);

    bf16x8 ap[4];
#pragma unroll
    for (int ks2 = 0; ks2 < 4; ks2++)
      ap[ks2] = *(const bf16x8*)&lPw[l15 * 136 + ks2 * 32 + q4 * 8];
#pragma unroll
    for (int db = 0; db < 4; db++) {
#pragma unroll
      for (int ks2 = 0; ks2 < 4; ks2++) {
        bf16x8 bv = *(const bf16x8*)&lV[(db * 16 + l15) * 136 + ks2 * 32 + q4 * 8];
        vacc[db] = __builtin_amdgcn_mfma_f32_16x16x32_bf16(ap[ks2], bv, vacc[db], 0, 0, 0);
      }
    }
  }

  float inv[4];
#pragma unroll
  for (int r = 0; r < 4; r++) inv[r] = 1.0f / l_sum[r];
#pragma unroll
  for (int db = 0; db < 4; db++)
#pragma unroll
    for (int r = 0; r < 4; r++) {
      size_t idx = (size_t)(b * 2048 + q0 + w * 16 + q4 * 4 + r) * 1024 +
                   h * 64 + db * 16 + l15;
      ctx[idx] = f2bf(vacc[db][r] * inv[r]);
    }
}

// ---------------------------------------------------------------------------
// Launch
// ---------------------------------------------------------------------------
extern "C" void kernel_launch(void* const* d_in, const int* in_sizes, int n_in,
                              void* d_out, int out_size, void* d_ws, size_t ws_size,
                              hipStream_t stream) {
  (void)in_sizes; (void)n_in; (void)out_size; (void)ws_size;
  const float* inputs  = (const float*)d_in[0];
  const float* wq      = (const float*)d_in[1];
  const float* wk      = (const float*)d_in[2];
  const float* wv      = (const float*)d_in[3];
  const float* wo      = (const float*)d_in[4];
  const float* wi      = (const float*)d_in[5];
  const float* wmo     = (const float*)d_in[6];
  const float* rel_emb = (const float*)d_in[7];
  float* out = (float*)d_out;
  char* ws = (char*)d_ws;

  const size_t MB = 1ull << 20;
  short* x16    = (short*)(ws + 0);        // 16 MB
  short* qkv    = (short*)(ws + 16 * MB);  // 48 MB
  short* hidden = (short*)(ws + 16 * MB);  // 64 MB overlay (qkv+vT dead then)
  short* vT     = (short*)(ws + 64 * MB);  // 16 MB
  short* wqkvt  = (short*)(ws + 80 * MB);  // 6 MB
  short* wot    = (short*)(ws + 86 * MB);  // 2 MB
  short* wit    = (short*)(ws + 88 * MB);  // 8 MB
  short* wmot   = (short*)(ws + 96 * MB);  // 8 MB
  float* btab   = (float*)(ws + 104 * MB); // 128 KB
  short* ctx    = (short*)(ws + 105 * MB); // 16 MB

  cvt_x_kernel<<<8192, 256, 0, stream>>>(inputs, x16);
  transpose_f2b_kernel<<<dim3(32, 32), 256, 0, stream>>>(wq, wqkvt, 1024, 1024);
  transpose_f2b_kernel<<<dim3(32, 32), 256, 0, stream>>>(wk, wqkvt + 1024 * 1024, 1024, 1024);
  transpose_f2b_kernel<<<dim3(32, 32), 256, 0, stream>>>(wv, wqkvt + 2 * 1024 * 1024, 1024, 1024);
  transpose_f2b_kernel<<<dim3(32, 32), 256, 0, stream>>>(wo, wot, 1024, 1024);
  transpose_f2b_kernel<<<dim3(128, 32), 256, 0, stream>>>(wi, wit, 1024, 4096);
  transpose_f2b_kernel<<<dim3(32, 128), 256, 0, stream>>>(wmo, wmot, 4096, 1024);
  bias_kernel<<<128, 256, 0, stream>>>(rel_emb, btab);

  // qkv = x @ [wq|wk|wv]
  gemm_bt_kernel<0><<<dim3(24, 64), 256, 0, stream>>>(x16, wqkvt, 3072, 1024,
                                                      nullptr, qkv, nullptr, nullptr);
  transpose_v_kernel<<<dim3(64, 2, 64), 256, 0, stream>>>(qkv, vT);
  attn_kernel<<<dim3(64, 32), 256, 0, stream>>>(qkv, vT, btab, ctx);
  // attn_out = ctx @ wo -> d_out (fp32 scratch)
  gemm_bt_kernel<2><<<dim3(8, 64), 256, 0, stream>>>(ctx, wot, 1024, 1024,
                                                     out, nullptr, nullptr, nullptr);
  // hidden = relu(x @ wi)
  gemm_bt_kernel<1><<<dim3(32, 64), 256, 0, stream>>>(x16, wit, 4096, 1024,
                                                      nullptr, hidden, nullptr, nullptr);
  // out = hidden @ wmo + inputs + attn_out
  gemm_bt_kernel<3><<<dim3(8, 64), 256, 0, stream>>>(hidden, wmot, 1024, 4096,
                                                     out, nullptr, inputs, out);
}